// Round 9
// baseline (296.020 us; speedup 1.0000x reference)
//
#include <hip/hip_runtime.h>

// DGODE — round 16 (resubmit; round-8 bench failed on GPU acquisition).
//   Prologue folding + stage-loop latency hiding.
//   Round 15 measured: fused_ode 140us (cached single-write snapshots work:
//   FETCH 77->25.6MB); ~8.75us/stage vs ~1.5us compute -> handoff chain bound.
//   Budget: ~43us harness fill + ~65us prologue + 140us fused.
//   This round:
//   - build_band folded into fused_ode AFTER h0 publish (r13's bit-identical
//     band code, but overlapping the first handoff instead of serializing);
//   - feat->featc copy skipped when input already bf16 (h0 reads feat direct);
//   - prep2 folded into prep's last block (one less launch);
//   - stage loop: GEMM1 own-hs half (kf 0..3, order preserved) hoisted BEFORE
//     the flag wait; per-wave spin (lanes 0..19 each wave) + compiler fence
//     replaces spin+block-barrier -> 3 barriers/stage instead of 4.
// Same MFMA sequence per (m,n,k), same fp32 expression order => bit-identical
// output (absmax 0.015625).

typedef unsigned short u16;
typedef unsigned long long u64;
typedef __attribute__((ext_vector_type(8))) short bf16x8v;
typedef __attribute__((ext_vector_type(4))) float f32x4;

#define MFMA16(a, b, c) __builtin_amdgcn_mfma_f32_16x16x32_bf16(a, b, c, 0, 0, 0)

#define BN 4096
#define HN 128
#define DIN 1856
#define TILEW 320

__device__ __forceinline__ float bf2f(u16 u) {
  union { unsigned u; float f; } v; v.u = ((unsigned)u) << 16; return v.f;
}
__device__ __forceinline__ u16 f2bf(float f) {
  union { float f; unsigned u; } v; v.f = f;
  unsigned u = v.u;
  return (u16)((u + 0x7fffu + ((u >> 16) & 1u)) >> 16);  // RNE
}
__device__ __forceinline__ float ldx(const void* p, long idx, int isf) {
  return isf ? ((const float*)p)[idx] : bf2f(((const u16*)p)[idx]);
}

// coherent (LLC-point) 8B store, no cache maintenance (producer publish path)
__device__ __forceinline__ void cstore8(u16* p, u64 v) {
  __hip_atomic_store((u64*)p, v, __ATOMIC_RELAXED, __HIP_MEMORY_SCOPE_AGENT);
}

// ---------- per-array dtype detection (parallel) + syncf zeroing ----------
__global__ __launch_bounds__(256) void detect(
    const void* a0, const void* a1, const void* a2, const void* a3,
    const void* a4, const void* a5, const void* a6, const void* a7,
    const unsigned* spk_raw, int* flags, int* syncf) {
  __shared__ int part[256];
  const int b = blockIdx.x, t = threadIdx.x;
  int cnt = 0;
  if (b < 8) {
    const void* arr[8] = {a0, a1, a2, a3, a4, a5, a6, a7};
    const int nel[8] = {BN * DIN, BN * 3, DIN * HN, HN, 2 * HN * HN, HN, HN * HN, HN};
    const u16* p = (const u16*)arr[b];
    int ns = nel[b] / 2; if (ns > 512) ns = 512;
    for (int e = t; e < ns; e += 256) {
      unsigned ex = (p[2 * e] >> 7) & 0xFFu;
      if (ex < 64u) cnt++;
    }
  } else if (b == 8) {
    for (int e = t; e < 512; e += 256)
      if (spk_raw[2 * e + 1] != 0u) cnt++;
  } else {
    syncf[t] = 0;          // b == 9: zero the 256 per-tile stage flags
    return;
  }
  part[t] = cnt;
  __syncthreads();
  #pragma unroll
  for (int o = 128; o > 0; o >>= 1) {
    if (t < o) part[t] += part[t + o];
    __syncthreads();
  }
  if (t == 0) {
    if (b < 8) flags[b] = (part[0] >= 2) ? 1 : 0;   // 1 = fp32
    else       flags[9] = (part[0] == 0) ? 1 : 0;   // 1 = int64 spk
  }
}

// ---------- canonicalize + bias classification (prep2 folded as last block) ----------
#define FEATBLK 3712   // 4096*1856 / 8 / 256
#define NWBLK 1184     // (237568+32768+16384+12288+4096)/256
__global__ __launch_bounds__(256) void prep(
    const void* feat, const void* Wp, const void* W1, const void* W2,
    const void* masks, const void* spk,
    const void* x0, const void* x1, const void* x2,
    const int* __restrict__ flags,
    u16* featc, u16* WpT, u16* W1T, u16* W2T, float* masks_c, int* spk_c,
    float* bp_c, float* b1c, float* b2c) {
  __shared__ float mxs[3][64];
  __shared__ int ord[3];
  const int blk = blockIdx.x, t = threadIdx.x;
  if (blk < FEATBLK) {
    if (!flags[0]) return;            // bf16 input: fused h0 reads feat directly
    long e = ((long)blk * 256 + t) * 8;
    const float* pf = (const float*)feat + e;
    u16 r[8];
    #pragma unroll
    for (int k = 0; k < 8; k++) r[k] = f2bf(pf[k]);
    *(bf16x8v*)(featc + e) = *(bf16x8v*)r;
    return;
  }
  if (blk == FEATBLK + NWBLK) {       // ---- prep2 body ----
    const void* bs[3] = {x0, x1, x2};
    const int fl[3] = {flags[3], flags[5], flags[7]};
    if (t < 192) {
      int a = t / 64, e = t % 64;
      mxs[a][e] = fmaxf(fabsf(ldx(bs[a], e, fl[a])), fabsf(ldx(bs[a], e + 64, fl[a])));
    }
    __syncthreads();
    if (t == 0) {
      float mx[3];
      for (int a = 0; a < 3; a++) {
        float m = 0.f;
        for (int e = 0; e < 64; e++) m = fmaxf(m, mxs[a][e]);
        mx[a] = m;
      }
      int imin = 0, imax = 0;
      for (int k = 1; k < 3; k++) { if (mx[k] < mx[imin]) imin = k; if (mx[k] > mx[imax]) imax = k; }
      int imid = 3 - imin - imax;
      if (imin == imax) { imin = 0; imid = 1; imax = 2; }
      ord[0] = imin; ord[1] = imid; ord[2] = imax;
    }
    __syncthreads();
    if (t < HN) {
      bp_c[t] = ldx(bs[ord[0]], t, fl[ord[0]]);
      b1c[t]  = ldx(bs[ord[1]], t, fl[ord[1]]);
      b2c[t]  = ldx(bs[ord[2]], t, fl[ord[2]]);
    }
    return;
  }
  long e = (long)(blk - FEATBLK) * 256 + t;
  const int nWp = DIN * HN, nW1 = 2 * HN * HN, nW2 = HN * HN, nM = BN * 3;
  if (e < nWp) {  // e = input index k*HN+o; coalesced read, strided write
    int k = e >> 7, o = e & 127;
    WpT[(long)o * DIN + k] = f2bf(ldx(Wp, e, flags[2]));
    return;
  }
  e -= nWp;
  if (e < nW1) { int k = e >> 7, o = e & 127; W1T[(long)o * 256 + k] = f2bf(ldx(W1, e, flags[4])); return; }
  e -= nW1;
  if (e < nW2) { int k = e >> 7, o = e & 127; W2T[(long)o * 128 + k] = f2bf(ldx(W2, e, flags[6])); return; }
  e -= nW2;
  if (e < nM) { masks_c[e] = ldx(masks, e, flags[1]); return; }
  e -= nM;
  if (e < BN) spk_c[e] = flags[9] ? ((const int*)spk)[2 * e] : ((const int*)spk)[e];
}

// ---------- adjacency ----------
__device__ __forceinline__ float adj_raw(int i, int j, int si, float m0, float m1, float m2,
                                         const int* __restrict__ spk,
                                         const float* __restrict__ mk) {
  if (i == j) return 1.0f;
  float t = expf(-0.1f * fabsf((float)(i - j)));
  if (spk[j] == si) return 0.8f * t;
  float ms = fabsf(m0 - mk[j * 3]) + fabsf(m1 - mk[j * 3 + 1]) + fabsf(m2 - mk[j * 3 + 2]);
  return 0.5f * t * (1.0f - ms * (1.0f / 3.0f));
}

// snapshot buffer geometry (u16 units): [4096 guard][HN*BN data][4096 guard]
#define SNAP_ELEMS ((size_t)HN * BN + 8192)

// ---------- fused band-build + h0 + 16 RK4 stages ----------
// Snapshot k lives in its own single-write buffer: h0 -> snap 0; stage s
// output -> snap s+1. Stage s reads snap s from tiles tile-8..tile+11.
// Flag value = snapshots published (1 = h0, s+2 = stage s done).
__global__ __launch_bounds__(512, 2) void fused_ode(
    const void* __restrict__ feat, const int* __restrict__ flags,
    const u16* __restrict__ featc, const u16* __restrict__ WpT,
    const float* __restrict__ bp_c,
    const int* __restrict__ spk, const float* __restrict__ mk,
    const u16* __restrict__ W1T, const u16* __restrict__ W2T,
    const float* __restrict__ b1c, const float* __restrict__ b2c,
    u16* __restrict__ hsb, float* __restrict__ outp,
    int* __restrict__ syncf) {
  __shared__ u16 hc[16][264];        // [hs(0:128) | agg(128:256)] i-major
  __shared__ u16 zt[16][136];        // tanh output i-major
  __shared__ float part[16][257];    // band row partial sums (pad 1)
  __shared__ float invs[16];

  const int tid = threadIdx.x, w = tid >> 6, lane = tid & 63;
  const int m = lane & 15, q = lane >> 4;
  // XCD-aware tile swizzle (perf heuristic; correctness placement-independent)
  const int blk = blockIdx.x;
  const int tile = ((blk & 7) << 5) | (blk >> 3);
  const int r0 = tile * 16, jb = r0 - 128;
  const int n0 = w * 16 + m;
  const int i0 = r0 + q * 4;
  const long base = (long)n0 * BN + i0;

  // neighbor tile for this lane's spin slot (lanes 0..19 of EVERY wave)
  int nbr = tile - 8 + lane;
  nbr = nbr < 0 ? 0 : (nbr > 255 ? 255 : nbr);

  // persistent weight registers
  bf16x8v w1r[8], w2r[4], bnd[10];
  {
    const u16* w1row = W1T + (long)n0 * 256;
    #pragma unroll
    for (int kf = 0; kf < 8; kf++) {
      int k = (kf >> 1) * 64 + (kf & 1) * 32 + q * 8;
      w1r[kf] = *(const bf16x8v*)(w1row + k);
    }
    const u16* w2row = W2T + (long)n0 * 128;
    #pragma unroll
    for (int kf = 0; kf < 4; kf++) {
      int k = (kf >> 1) * 64 + (kf & 1) * 32 + q * 8;
      w2r[kf] = *(const bf16x8v*)(w2row + k);
    }
  }
  const float b1v = b1c[n0], b2v = b2c[n0];

  // ---- h0 = feat @ Wp + bp (identical bits: featc when fp32, raw when bf16) ----
  f32x4 hb;
  {
    const u16* fbase = flags[0] ? featc : (const u16*)feat;
    f32x4 a0 = {0, 0, 0, 0};
    const u16* arow = fbase + (long)(r0 + m) * DIN;
    const u16* brow = WpT + (long)n0 * DIN;
    #pragma unroll 4
    for (int kf = 0; kf < 58; kf++) {   // 58 * 32 = 1856
      int k = (kf >> 1) * 64 + (kf & 1) * 32 + q * 8;
      bf16x8v a = *(const bf16x8v*)(arow + k);
      bf16x8v b = *(const bf16x8v*)(brow + k);
      a0 = MFMA16(a, b, a0);
    }
    a0 += bp_c[n0];
    hb = a0;
  }
  f32x4 acc = {0, 0, 0, 0};
  {
    u16* snap0 = hsb + 4096;                           // snapshot 0 data
    ushort4 hsv;
    hsv.x = f2bf(hb[0]); hsv.y = f2bf(hb[1]); hsv.z = f2bf(hb[2]); hsv.w = f2bf(hb[3]);
    union { ushort4 s; u64 q8; } pu; pu.s = hsv;
    cstore8(&snap0[base], pu.q8);                      // cross-block snapshot 0
    hc[q * 4 + 0][n0] = hsv.x; hc[q * 4 + 1][n0] = hsv.y;  // own-block, direct
    hc[q * 4 + 2][n0] = hsv.z; hc[q * 4 + 3][n0] = hsv.w;
  }
  asm volatile("s_waitcnt vmcnt(0)" ::: "memory");     // hs stores at LLC
  __syncthreads();
  if (tid == 0)
    __hip_atomic_store(&syncf[tile], 1, __ATOMIC_RELAXED, __HIP_MEMORY_SCOPE_AGENT);

  // ---- band build (bit-identical to build_band; overlaps neighbors' h0) ----
  {
    const int tp = tid & 255, rhalf = tid >> 8;
    #pragma unroll 1
    for (int p8 = 0; p8 < 8; p8++) {
      const int r = rhalf + 2 * p8;
      const int i = r0 + r;
      const int si = spk[i];
      const float m0 = mk[i * 3], m1 = mk[i * 3 + 1], m2 = mk[i * 3 + 2];
      float ssum = 0.f;
      for (int jj = 0; jj < 16; jj++)
        ssum += adj_raw(i, tp + (jj << 8), si, m0, m1, m2, spk, mk);
      part[r][tp] = ssum;
    }
  }
  __syncthreads();
  if (tid < 16) {
    float tot = 0.f;
    for (int k = 0; k < 256; k++) tot += part[tid][k];   // serial: original order
    invs[tid] = 1.0f / (tot + 1e-8f);
  }
  __syncthreads();
  {
    const int i = r0 + m;
    const int si = spk[i];
    const float m0 = mk[i * 3], m1 = mk[i * 3 + 1], m2 = mk[i * 3 + 2];
    const float inv = invs[m];
    #pragma unroll
    for (int kf = 0; kf < 10; kf++) {
      int k = (kf >> 1) * 64 + (kf & 1) * 32 + q * 8;
      #pragma unroll
      for (int e = 0; e < 8; e++) {
        int j = jb + k + e;
        float v = 0.f;
        if (j >= 0 && j < BN) v = adj_raw(i, j, si, m0, m1, m2, spk, mk) * inv;
        bnd[kf][e] = (short)f2bf(v);
      }
    }
  }

  const float dt6 = 0.25f / 6.0f;

  #pragma unroll 1
  for (int s = 0; s < 16; s++) {
    const int sub = s & 3;

    // GEMM1 own-hs half (kf 0..3) — no neighbor dependency; order preserved
    f32x4 z0 = {0, 0, 0, 0};
    #pragma unroll
    for (int kf = 0; kf < 4; kf++) {
      int k = (kf >> 1) * 64 + (kf & 1) * 32 + q * 8;
      bf16x8v a = *(const bf16x8v*)&hc[m][k];
      z0 = MFMA16(a, w1r[kf], z0);
    }

    // per-wave wait for the 20 producer tiles' snapshot s (no block barrier)
    if (lane < 20) {
      while (__hip_atomic_load(&syncf[nbr], __ATOMIC_RELAXED,
                               __HIP_MEMORY_SCOPE_AGENT) < s + 1)
        __builtin_amdgcn_s_sleep(1);
    }
    asm volatile("" ::: "memory");   // keep window loads below the spin

    // phase 1: banded agg — A from band regs, B via plain cached loads
    f32x4 g0 = {0, 0, 0, 0};
    const u16* hrow = hsb + (size_t)s * SNAP_ELEMS + 4096 + (long)n0 * BN + jb;
    #pragma unroll
    for (int kf = 0; kf < 10; kf++) {
      int k = (kf >> 1) * 64 + (kf & 1) * 32 + q * 8;
      bf16x8v b = *(const bf16x8v*)(hrow + k);
      g0 = MFMA16(bnd[kf], b, g0);
    }
    #pragma unroll
    for (int r = 0; r < 4; r++) hc[q * 4 + r][128 + n0] = f2bf(g0[r]);
    __syncthreads();

    // GEMM1 agg half (kf 4..7) — completes z0 in original accumulation order
    #pragma unroll
    for (int kf = 4; kf < 8; kf++) {
      int k = (kf >> 1) * 64 + (kf & 1) * 32 + q * 8;
      bf16x8v a = *(const bf16x8v*)&hc[m][k];
      z0 = MFMA16(a, w1r[kf], z0);
    }
    #pragma unroll
    for (int r = 0; r < 4; r++) zt[q * 4 + r][n0] = f2bf(tanhf(z0[r] + b1v));
    __syncthreads();

    // GEMM2: k = z @ W2 — A from LDS, B from persistent regs
    f32x4 k0 = {0, 0, 0, 0};
    #pragma unroll
    for (int kf = 0; kf < 4; kf++) {
      int k = (kf >> 1) * 64 + (kf & 1) * 32 + q * 8;
      bf16x8v a = *(const bf16x8v*)&zt[m][k];
      k0 = MFMA16(a, w2r[kf], k0);
    }
    f32x4 kv = k0;
    kv += b2v;

    // RK4 update — identical fp32 expression order to round 9
    f32x4 hn;
    if (sub == 0)      { acc = 1.f * kv;  hn = hb + 0.125f * kv; }
    else if (sub == 1) { acc += 2.f * kv; hn = hb + 0.125f * kv; }
    else if (sub == 2) { acc += 2.f * kv; hn = hb + 0.25f  * kv; }
    else {
      hn = hb + dt6 * (acc + kv);
      hb = hn;
      if (s == 15) {
        #pragma unroll
        for (int r = 0; r < 4; r++) outp[(long)(i0 + r) * HN + n0] = hn[r];  // fp32
      }
    }

    if (s < 15) {
      // publish snapshot s+1: LLC store (neighbors) + LDS left half (own)
      u16* snapw = hsb + (size_t)(s + 1) * SNAP_ELEMS + 4096;
      ushort4 hsv;
      hsv.x = f2bf(hn[0]); hsv.y = f2bf(hn[1]); hsv.z = f2bf(hn[2]); hsv.w = f2bf(hn[3]);
      union { ushort4 s4; u64 q8; } pu; pu.s4 = hsv;
      cstore8(&snapw[base], pu.q8);
      hc[q * 4 + 0][n0] = hsv.x; hc[q * 4 + 1][n0] = hsv.y;
      hc[q * 4 + 2][n0] = hsv.z; hc[q * 4 + 3][n0] = hsv.w;
      asm volatile("s_waitcnt vmcnt(0)" ::: "memory");   // hs stores at LLC
      __syncthreads();
      if (tid == 0)
        __hip_atomic_store(&syncf[tile], s + 2, __ATOMIC_RELAXED, __HIP_MEMORY_SCOPE_AGENT);
    }
  }
}

// ---------- launch ----------
extern "C" void kernel_launch(void* const* d_in, const int* in_sizes, int n_in,
                              void* d_out, int out_size, void* d_ws, size_t ws_size,
                              hipStream_t stream) {
  const void* feat = nullptr; const void* spk = nullptr; const void* masks = nullptr;
  const void* Wp = nullptr; const void* W1 = nullptr; const void* W2 = nullptr;
  const void* bias[3] = {nullptr, nullptr, nullptr};
  int nb = 0;
  for (int k = 0; k < n_in; k++) {
    switch (in_sizes[k]) {
      case BN * DIN:    feat = d_in[k]; break;
      case BN:          spk = d_in[k]; break;
      case BN * 3:      masks = d_in[k]; break;
      case DIN * HN:    Wp = d_in[k]; break;
      case 2 * HN * HN: W1 = d_in[k]; break;
      case HN * HN:     W2 = d_in[k]; break;
      default:          if (in_sizes[k] == HN && nb < 3) bias[nb++] = d_in[k]; break;
    }
  }
  float* out = (float*)d_out;

  char* p = (char*)d_ws;
  int*   flags   = (int*)p;   p += 64;
  int*   spk_c   = (int*)p;   p += BN * 4;
  float* masks_c = (float*)p; p += BN * 3 * 4;
  float* bp_c    = (float*)p; p += 512;
  float* b1c     = (float*)p; p += 512;
  float* b2c     = (float*)p; p += 512;
  int*   syncf   = (int*)p;   p += 1024;                    // 256 stage flags
  u16*   featc   = (u16*)p;   p += (size_t)BN * DIN * 2;    // 15,204,352
  u16*   WpT     = (u16*)p;   p += (size_t)HN * DIN * 2;
  u16*   W1T     = (u16*)p;   p += (size_t)HN * 256 * 2;
  u16*   W2T     = (u16*)p;   p += (size_t)HN * HN * 2;
  u16*   hsb     = (u16*)p;   p += 16 * SNAP_ELEMS * 2;     // 16 snapshots ~17 MB
  (void)ws_size; (void)out_size;                            // total ~34 MB

  detect<<<10, 256, 0, stream>>>(feat, masks, Wp, bias[0], W1, bias[1], W2, bias[2],
                                 (const unsigned*)spk, flags, syncf);
  prep<<<FEATBLK + NWBLK + 1, 256, 0, stream>>>(
      feat, Wp, W1, W2, masks, spk, bias[0], bias[1], bias[2], flags,
      featc, WpT, W1T, W2T, masks_c, spk_c, bp_c, b1c, b2c);

  // Regular launch: 256 blocks on 256 CUs (1 block/CU by resource fit) —
  // co-residency without the cooperative-launch overhead.
  fused_ode<<<dim3(BN / 16), dim3(512), 0, stream>>>(
      feat, flags, featc, WpT, bp_c, spk_c, masks_c, W1T, W2T, b1c, b2c,
      hsb, out, syncf);
}

// Round 10
// 251.525 us; speedup vs baseline: 1.1769x; 1.1769x over previous
//
#include <hip/hip_runtime.h>

// DGODE — round 17: recombine measured-good pieces.
//   r16 post-mortem: band-fold into fused regressed AGAIN (+77us: 65k expf/blk
//   at 8 waves/CU on every block's critical path + 160-poller flag storm);
//   but the prologue reorg (prep2 fold, launch removal) saved ~30us.
//   This round:
//   - fused_ode = EXACT r15 body (measured 140us: 20-thread spin + block
//     barrier, band from global) + GEMM1 own-half hoist (kf0..3 before the
//     spin; accumulation order kf0->7 preserved => bit-identical);
//   - build_band absorbed as 4096 extra blocks of prep (full occupancy),
//     reading RAW masks/spk with inline conversion (identical values =>
//     identical band bits); masks_c/spk_c dropped (dead);
//   - detect zeroes syncf; prep2 stays folded in prep.
// Same MFMA sequence per (m,n,k), same fp32 expression order => bit-identical
// output (absmax 0.015625).

typedef unsigned short u16;
typedef unsigned long long u64;
typedef __attribute__((ext_vector_type(8))) short bf16x8v;
typedef __attribute__((ext_vector_type(4))) float f32x4;

#define MFMA16(a, b, c) __builtin_amdgcn_mfma_f32_16x16x32_bf16(a, b, c, 0, 0, 0)

#define BN 4096
#define HN 128
#define DIN 1856
#define TILEW 320

__device__ __forceinline__ float bf2f(u16 u) {
  union { unsigned u; float f; } v; v.u = ((unsigned)u) << 16; return v.f;
}
__device__ __forceinline__ u16 f2bf(float f) {
  union { float f; unsigned u; } v; v.f = f;
  unsigned u = v.u;
  return (u16)((u + 0x7fffu + ((u >> 16) & 1u)) >> 16);  // RNE
}
__device__ __forceinline__ float ldx(const void* p, long idx, int isf) {
  return isf ? ((const float*)p)[idx] : bf2f(((const u16*)p)[idx]);
}
__device__ __forceinline__ int ldspk(const void* spk, int j, int i64) {
  return i64 ? ((const int*)spk)[2 * j] : ((const int*)spk)[j];
}

// coherent (LLC-point) 8B store, no cache maintenance (producer publish path)
__device__ __forceinline__ void cstore8(u16* p, u64 v) {
  __hip_atomic_store((u64*)p, v, __ATOMIC_RELAXED, __HIP_MEMORY_SCOPE_AGENT);
}

// ---------- per-array dtype detection (parallel) + syncf zeroing ----------
__global__ __launch_bounds__(256) void detect(
    const void* a0, const void* a1, const void* a2, const void* a3,
    const void* a4, const void* a5, const void* a6, const void* a7,
    const unsigned* spk_raw, int* flags, int* syncf) {
  __shared__ int part[256];
  const int b = blockIdx.x, t = threadIdx.x;
  int cnt = 0;
  if (b < 8) {
    const void* arr[8] = {a0, a1, a2, a3, a4, a5, a6, a7};
    const int nel[8] = {BN * DIN, BN * 3, DIN * HN, HN, 2 * HN * HN, HN, HN * HN, HN};
    const u16* p = (const u16*)arr[b];
    int ns = nel[b] / 2; if (ns > 512) ns = 512;
    for (int e = t; e < ns; e += 256) {
      unsigned ex = (p[2 * e] >> 7) & 0xFFu;
      if (ex < 64u) cnt++;
    }
  } else if (b == 8) {
    for (int e = t; e < 512; e += 256)
      if (spk_raw[2 * e + 1] != 0u) cnt++;
  } else {
    syncf[t] = 0;          // b == 9: zero the 256 per-tile stage flags
    return;
  }
  part[t] = cnt;
  __syncthreads();
  #pragma unroll
  for (int o = 128; o > 0; o >>= 1) {
    if (t < o) part[t] += part[t + o];
    __syncthreads();
  }
  if (t == 0) {
    if (b < 8) flags[b] = (part[0] >= 2) ? 1 : 0;   // 1 = fp32
    else       flags[9] = (part[0] == 0) ? 1 : 0;   // 1 = int64 spk
  }
}

// ---------- adjacency from RAW inputs (identical values to canonical) ----------
__device__ __forceinline__ float adjr(int i, int j, int si, float m0, float m1, float m2,
                                      const void* __restrict__ spk,
                                      const void* __restrict__ mk, int fm, int fs) {
  if (i == j) return 1.0f;
  float t = expf(-0.1f * fabsf((float)(i - j)));
  if (ldspk(spk, j, fs) == si) return 0.8f * t;
  float ms = fabsf(m0 - ldx(mk, (long)j * 3, fm)) +
             fabsf(m1 - ldx(mk, (long)j * 3 + 1, fm)) +
             fabsf(m2 - ldx(mk, (long)j * 3 + 2, fm));
  return 0.5f * t * (1.0f - ms * (1.0f / 3.0f));
}

// ---------- canonicalize + prep2 + band rows (one full-occupancy kernel) ----------
#define FEATBLK 3712   // 4096*1856 / 8 / 256
#define NWBLK 1120     // (237568 + 32768 + 16384) / 256
__global__ __launch_bounds__(256) void prep(
    const void* feat, const void* Wp, const void* W1, const void* W2,
    const void* masks, const void* spk,
    const void* x0, const void* x1, const void* x2,
    const int* __restrict__ flags,
    u16* featc, u16* WpT, u16* W1T, u16* W2T,
    float* bp_c, float* b1c, float* b2c, u16* __restrict__ band) {
  __shared__ float part[256];
  __shared__ float invs;
  __shared__ float mxs[3][64];
  __shared__ int ord[3];
  const int blk = blockIdx.x, t = threadIdx.x;
  if (blk < FEATBLK) {
    if (!flags[0]) return;            // bf16 input: fused h0 reads feat directly
    long e = ((long)blk * 256 + t) * 8;
    const float* pf = (const float*)feat + e;
    u16 r[8];
    #pragma unroll
    for (int k = 0; k < 8; k++) r[k] = f2bf(pf[k]);
    *(bf16x8v*)(featc + e) = *(bf16x8v*)r;
    return;
  }
  if (blk < FEATBLK + NWBLK) {        // ---- weight transposes ----
    long e = (long)(blk - FEATBLK) * 256 + t;
    const int nWp = DIN * HN, nW1 = 2 * HN * HN;
    if (e < nWp) {  // e = input index k*HN+o; coalesced read, strided write
      int k = e >> 7, o = e & 127;
      WpT[(long)o * DIN + k] = f2bf(ldx(Wp, e, flags[2]));
      return;
    }
    e -= nWp;
    if (e < nW1) { int k = e >> 7, o = e & 127; W1T[(long)o * 256 + k] = f2bf(ldx(W1, e, flags[4])); return; }
    e -= nW1;
    { int k = e >> 7, o = e & 127; W2T[(long)o * 128 + k] = f2bf(ldx(W2, e, flags[6])); }
    return;
  }
  if (blk == FEATBLK + NWBLK) {       // ---- prep2 body ----
    const void* bs[3] = {x0, x1, x2};
    const int fl[3] = {flags[3], flags[5], flags[7]};
    if (t < 192) {
      int a = t / 64, e = t % 64;
      mxs[a][e] = fmaxf(fabsf(ldx(bs[a], e, fl[a])), fabsf(ldx(bs[a], e + 64, fl[a])));
    }
    __syncthreads();
    if (t == 0) {
      float mx[3];
      for (int a = 0; a < 3; a++) {
        float m = 0.f;
        for (int e = 0; e < 64; e++) m = fmaxf(m, mxs[a][e]);
        mx[a] = m;
      }
      int imin = 0, imax = 0;
      for (int k = 1; k < 3; k++) { if (mx[k] < mx[imin]) imin = k; if (mx[k] > mx[imax]) imax = k; }
      int imid = 3 - imin - imax;
      if (imin == imax) { imin = 0; imid = 1; imax = 2; }
      ord[0] = imin; ord[1] = imid; ord[2] = imax;
    }
    __syncthreads();
    if (t < HN) {
      bp_c[t] = ldx(bs[ord[0]], t, fl[ord[0]]);
      b1c[t]  = ldx(bs[ord[1]], t, fl[ord[1]]);
      b2c[t]  = ldx(bs[ord[2]], t, fl[ord[2]]);
    }
    return;
  }
  // ---- band row (bit-identical to build_band; raw-input reads) ----
  {
    const int i = blk - FEATBLK - NWBLK - 1;
    const int fm = flags[1], fs = flags[9];
    const int si = ldspk(spk, i, fs);
    const float m0 = ldx(masks, (long)i * 3, fm);
    const float m1 = ldx(masks, (long)i * 3 + 1, fm);
    const float m2 = ldx(masks, (long)i * 3 + 2, fm);
    float s = 0.f;
    for (int j = t; j < BN; j += 256) s += adjr(i, j, si, m0, m1, m2, spk, masks, fm, fs);
    part[t] = s;
    __syncthreads();
    if (t == 0) {
      float tot = 0.f;
      for (int k = 0; k < 256; k++) tot += part[k];   // serial: original order
      invs = 1.0f / (tot + 1e-8f);
    }
    __syncthreads();
    const float inv = invs;
    const int jbase = (i & ~15) - 128;
    for (int k = t; k < TILEW; k += 256) {
      int j = jbase + k;
      float v = 0.f;
      if (j >= 0 && j < BN) v = adjr(i, j, si, m0, m1, m2, spk, masks, fm, fs) * inv;
      band[(long)i * TILEW + k] = f2bf(v);
    }
  }
}

// snapshot buffer geometry (u16 units): [4096 guard][HN*BN data][4096 guard]
#define SNAP_ELEMS ((size_t)HN * BN + 8192)

// ---------- fused h0 + 16 RK4 stages (r15 body + GEMM1 own-half hoist) ----------
// Snapshot k lives in its own single-write buffer: h0 -> snap 0; stage s
// output -> snap s+1. Stage s reads snap s from tiles tile-8..tile+11.
// Flag value = snapshots published (1 = h0, s+2 = stage s done).
__global__ __launch_bounds__(512, 2) void fused_ode(
    const void* __restrict__ feat, const int* __restrict__ flags,
    const u16* __restrict__ featc, const u16* __restrict__ WpT,
    const float* __restrict__ bp_c, const u16* __restrict__ band,
    const u16* __restrict__ W1T, const u16* __restrict__ W2T,
    const float* __restrict__ b1c, const float* __restrict__ b2c,
    u16* __restrict__ hsb, float* __restrict__ outp,
    int* __restrict__ syncf) {
  __shared__ u16 hc[16][264];        // [hs(0:128) | agg(128:256)] i-major
  __shared__ u16 zt[16][136];        // tanh output i-major

  const int tid = threadIdx.x, w = tid >> 6, lane = tid & 63;
  const int m = lane & 15, q = lane >> 4;
  // XCD-aware tile swizzle (perf heuristic; correctness placement-independent)
  const int blk = blockIdx.x;
  const int tile = ((blk & 7) << 5) | (blk >> 3);
  const int r0 = tile * 16, jb = r0 - 128;
  const int n0 = w * 16 + m;
  const int i0 = r0 + q * 4;
  const long base = (long)n0 * BN + i0;

  // neighbor tile for this thread's spin slot (threads 0..19)
  int nbr = tile - 8 + tid;
  nbr = nbr < 0 ? 0 : (nbr > 255 ? 255 : nbr);

  // persistent operand registers (loaded once, reused all 16 stages)
  bf16x8v w1r[8], w2r[4], bnd[10];
  {
    const u16* w1row = W1T + (long)n0 * 256;
    #pragma unroll
    for (int kf = 0; kf < 8; kf++) {
      int k = (kf >> 1) * 64 + (kf & 1) * 32 + q * 8;
      w1r[kf] = *(const bf16x8v*)(w1row + k);
    }
    const u16* w2row = W2T + (long)n0 * 128;
    #pragma unroll
    for (int kf = 0; kf < 4; kf++) {
      int k = (kf >> 1) * 64 + (kf & 1) * 32 + q * 8;
      w2r[kf] = *(const bf16x8v*)(w2row + k);
    }
    const u16* bandrow = band + (long)tile * 5120 + m * TILEW;
    #pragma unroll
    for (int kf = 0; kf < 10; kf++) {
      int k = (kf >> 1) * 64 + (kf & 1) * 32 + q * 8;
      bnd[kf] = *(const bf16x8v*)(bandrow + k);
    }
  }
  const float b1v = b1c[n0], b2v = b2c[n0];

  // ---- h0 = feat @ Wp + bp (identical bits: featc when fp32, raw when bf16) ----
  f32x4 hb;
  {
    const u16* fbase = flags[0] ? featc : (const u16*)feat;
    f32x4 a0 = {0, 0, 0, 0};
    const u16* arow = fbase + (long)(r0 + m) * DIN;
    const u16* brow = WpT + (long)n0 * DIN;
    #pragma unroll 4
    for (int kf = 0; kf < 58; kf++) {   // 58 * 32 = 1856
      int k = (kf >> 1) * 64 + (kf & 1) * 32 + q * 8;
      bf16x8v a = *(const bf16x8v*)(arow + k);
      bf16x8v b = *(const bf16x8v*)(brow + k);
      a0 = MFMA16(a, b, a0);
    }
    a0 += bp_c[n0];
    hb = a0;
  }
  f32x4 acc = {0, 0, 0, 0};
  {
    u16* snap0 = hsb + 4096;                           // snapshot 0 data
    ushort4 hsv;
    hsv.x = f2bf(hb[0]); hsv.y = f2bf(hb[1]); hsv.z = f2bf(hb[2]); hsv.w = f2bf(hb[3]);
    union { ushort4 s; u64 q8; } pu; pu.s = hsv;
    cstore8(&snap0[base], pu.q8);                      // cross-block snapshot 0
    hc[q * 4 + 0][n0] = hsv.x; hc[q * 4 + 1][n0] = hsv.y;  // own-block, direct
    hc[q * 4 + 2][n0] = hsv.z; hc[q * 4 + 3][n0] = hsv.w;
  }
  asm volatile("s_waitcnt vmcnt(0)" ::: "memory");     // hs stores at LLC
  __syncthreads();
  if (tid == 0)
    __hip_atomic_store(&syncf[tile], 1, __ATOMIC_RELAXED, __HIP_MEMORY_SCOPE_AGENT);

  const float dt6 = 0.25f / 6.0f;

  #pragma unroll 1
  for (int s = 0; s < 16; s++) {
    const int sub = s & 3;

    // GEMM1 own-hs half (kf 0..3) — no neighbor dependency; overlaps handoff
    f32x4 z0 = {0, 0, 0, 0};
    #pragma unroll
    for (int kf = 0; kf < 4; kf++) {
      int k = (kf >> 1) * 64 + (kf & 1) * 32 + q * 8;
      bf16x8v a = *(const bf16x8v*)&hc[m][k];
      z0 = MFMA16(a, w1r[kf], z0);
    }

    // ---- wait until the 20 producer tiles have published snapshot s ----
    if (tid < 20) {
      while (__hip_atomic_load(&syncf[nbr], __ATOMIC_RELAXED,
                               __HIP_MEMORY_SCOPE_AGENT) < s + 1)
        __builtin_amdgcn_s_sleep(1);
    }
    __syncthreads();

    // phase 1: banded agg — A from band regs, B via plain cached loads
    // (snapshot buffer is single-write: no stale copy can exist).
    f32x4 g0 = {0, 0, 0, 0};
    const u16* hrow = hsb + (size_t)s * SNAP_ELEMS + 4096 + (long)n0 * BN + jb;
    #pragma unroll
    for (int kf = 0; kf < 10; kf++) {
      int k = (kf >> 1) * 64 + (kf & 1) * 32 + q * 8;
      bf16x8v b = *(const bf16x8v*)(hrow + k);
      g0 = MFMA16(bnd[kf], b, g0);
    }
    #pragma unroll
    for (int r = 0; r < 4; r++) hc[q * 4 + r][128 + n0] = f2bf(g0[r]);
    __syncthreads();

    // GEMM1 agg half (kf 4..7) — completes z0 in original accumulation order
    #pragma unroll
    for (int kf = 4; kf < 8; kf++) {
      int k = (kf >> 1) * 64 + (kf & 1) * 32 + q * 8;
      bf16x8v a = *(const bf16x8v*)&hc[m][k];
      z0 = MFMA16(a, w1r[kf], z0);
    }
    #pragma unroll
    for (int r = 0; r < 4; r++) zt[q * 4 + r][n0] = f2bf(tanhf(z0[r] + b1v));
    __syncthreads();

    // GEMM2: k = z @ W2 — A from LDS, B from persistent regs
    f32x4 k0 = {0, 0, 0, 0};
    #pragma unroll
    for (int kf = 0; kf < 4; kf++) {
      int k = (kf >> 1) * 64 + (kf & 1) * 32 + q * 8;
      bf16x8v a = *(const bf16x8v*)&zt[m][k];
      k0 = MFMA16(a, w2r[kf], k0);
    }
    f32x4 kv = k0;
    kv += b2v;

    // RK4 update — identical fp32 expression order to round 9
    f32x4 hn;
    if (sub == 0)      { acc = 1.f * kv;  hn = hb + 0.125f * kv; }
    else if (sub == 1) { acc += 2.f * kv; hn = hb + 0.125f * kv; }
    else if (sub == 2) { acc += 2.f * kv; hn = hb + 0.25f  * kv; }
    else {
      hn = hb + dt6 * (acc + kv);
      hb = hn;
      if (s == 15) {
        #pragma unroll
        for (int r = 0; r < 4; r++) outp[(long)(i0 + r) * HN + n0] = hn[r];  // fp32
      }
    }

    if (s < 15) {
      // publish snapshot s+1: LLC store (neighbors) + LDS left half (own)
      u16* snapw = hsb + (size_t)(s + 1) * SNAP_ELEMS + 4096;
      ushort4 hsv;
      hsv.x = f2bf(hn[0]); hsv.y = f2bf(hn[1]); hsv.z = f2bf(hn[2]); hsv.w = f2bf(hn[3]);
      union { ushort4 s4; u64 q8; } pu; pu.s4 = hsv;
      cstore8(&snapw[base], pu.q8);
      hc[q * 4 + 0][n0] = hsv.x; hc[q * 4 + 1][n0] = hsv.y;
      hc[q * 4 + 2][n0] = hsv.z; hc[q * 4 + 3][n0] = hsv.w;
      asm volatile("s_waitcnt vmcnt(0)" ::: "memory");   // hs stores at LLC
      __syncthreads();
      if (tid == 0)
        __hip_atomic_store(&syncf[tile], s + 2, __ATOMIC_RELAXED, __HIP_MEMORY_SCOPE_AGENT);
    }
  }
}

// ---------- launch ----------
extern "C" void kernel_launch(void* const* d_in, const int* in_sizes, int n_in,
                              void* d_out, int out_size, void* d_ws, size_t ws_size,
                              hipStream_t stream) {
  const void* feat = nullptr; const void* spk = nullptr; const void* masks = nullptr;
  const void* Wp = nullptr; const void* W1 = nullptr; const void* W2 = nullptr;
  const void* bias[3] = {nullptr, nullptr, nullptr};
  int nb = 0;
  for (int k = 0; k < n_in; k++) {
    switch (in_sizes[k]) {
      case BN * DIN:    feat = d_in[k]; break;
      case BN:          spk = d_in[k]; break;
      case BN * 3:      masks = d_in[k]; break;
      case DIN * HN:    Wp = d_in[k]; break;
      case 2 * HN * HN: W1 = d_in[k]; break;
      case HN * HN:     W2 = d_in[k]; break;
      default:          if (in_sizes[k] == HN && nb < 3) bias[nb++] = d_in[k]; break;
    }
  }
  float* out = (float*)d_out;

  char* p = (char*)d_ws;
  int*   flags   = (int*)p;   p += 64;
  float* bp_c    = (float*)p; p += 512;
  float* b1c     = (float*)p; p += 512;
  float* b2c     = (float*)p; p += 512;
  int*   syncf   = (int*)p;   p += 1024;                    // 256 stage flags
  u16*   featc   = (u16*)p;   p += (size_t)BN * DIN * 2;    // 15,204,352
  u16*   WpT     = (u16*)p;   p += (size_t)HN * DIN * 2;
  u16*   W1T     = (u16*)p;   p += (size_t)HN * 256 * 2;
  u16*   W2T     = (u16*)p;   p += (size_t)HN * HN * 2;
  u16*   band    = (u16*)p;   p += (size_t)BN * TILEW * 2;
  u16*   hsb     = (u16*)p;   p += 16 * SNAP_ELEMS * 2;     // 16 snapshots ~17 MB
  (void)ws_size; (void)out_size;                            // total ~36 MB

  detect<<<10, 256, 0, stream>>>(feat, masks, Wp, bias[0], W1, bias[1], W2, bias[2],
                                 (const unsigned*)spk, flags, syncf);
  prep<<<FEATBLK + NWBLK + 1 + BN, 256, 0, stream>>>(
      feat, Wp, W1, W2, masks, spk, bias[0], bias[1], bias[2], flags,
      featc, WpT, W1T, W2T, bp_c, b1c, b2c, band);

  // Regular launch: 256 blocks on 256 CUs (1 block/CU by resource fit) —
  // co-residency without the cooperative-launch overhead.
  fused_ode<<<dim3(BN / 16), dim3(512), 0, stream>>>(
      feat, flags, featc, WpT, bp_c, band, W1T, W2T, b1c, b2c,
      hsb, out, syncf);
}

// Round 13
// 248.769 us; speedup vs baseline: 1.1899x; 1.0111x over previous
//
#include <hip/hip_runtime.h>

// DGODE — round 18 (3rd submit; rounds 11/12 failed on GPU acquisition).
//   Push-notification mailbox sync (r17 body otherwise).
//   r17 measured: fused_ode 140us, ~8.1us/stage vs ~3.5us latency model.
//   Theory: the residue is poll contention — 5120 pollers (20thr x 256blk)
//   on 256 SHARED flag addresses via uncached LLC atomic loads.
//   Fix: each block owns ONE inbox counter, polled by ONE thread (tid 0).
//   Producers push: after the publish barrier, lanes 0..19 fire-and-forget
//   one relaxed agent atomic_fetch_add to consumers tile-11+tid (valid only).
//   Consumer T waits inbox >= N_T*(s+1), N_T = exact in-range producer count.
//   Visibility unchanged from r15: hs drained to LLC before the add; snapshot
//   buffers single-write -> plain cached window loads stay legal.
// Same MFMA sequence per (m,n,k), same fp32 expression order => bit-identical
// output (absmax 0.015625).

typedef unsigned short u16;
typedef unsigned long long u64;
typedef __attribute__((ext_vector_type(8))) short bf16x8v;
typedef __attribute__((ext_vector_type(4))) float f32x4;

#define MFMA16(a, b, c) __builtin_amdgcn_mfma_f32_16x16x32_bf16(a, b, c, 0, 0, 0)

#define BN 4096
#define HN 128
#define DIN 1856
#define TILEW 320

__device__ __forceinline__ float bf2f(u16 u) {
  union { unsigned u; float f; } v; v.u = ((unsigned)u) << 16; return v.f;
}
__device__ __forceinline__ u16 f2bf(float f) {
  union { float f; unsigned u; } v; v.f = f;
  unsigned u = v.u;
  return (u16)((u + 0x7fffu + ((u >> 16) & 1u)) >> 16);  // RNE
}
__device__ __forceinline__ float ldx(const void* p, long idx, int isf) {
  return isf ? ((const float*)p)[idx] : bf2f(((const u16*)p)[idx]);
}
__device__ __forceinline__ int ldspk(const void* spk, int j, int i64) {
  return i64 ? ((const int*)spk)[2 * j] : ((const int*)spk)[j];
}

// coherent (LLC-point) 8B store, no cache maintenance (producer publish path)
__device__ __forceinline__ void cstore8(u16* p, u64 v) {
  __hip_atomic_store((u64*)p, v, __ATOMIC_RELAXED, __HIP_MEMORY_SCOPE_AGENT);
}

// ---------- per-array dtype detection (parallel) + inbox zeroing ----------
__global__ __launch_bounds__(256) void detect(
    const void* a0, const void* a1, const void* a2, const void* a3,
    const void* a4, const void* a5, const void* a6, const void* a7,
    const unsigned* spk_raw, int* flags, int* inbox) {
  __shared__ int part[256];
  const int b = blockIdx.x, t = threadIdx.x;
  int cnt = 0;
  if (b < 8) {
    const void* arr[8] = {a0, a1, a2, a3, a4, a5, a6, a7};
    const int nel[8] = {BN * DIN, BN * 3, DIN * HN, HN, 2 * HN * HN, HN, HN * HN, HN};
    const u16* p = (const u16*)arr[b];
    int ns = nel[b] / 2; if (ns > 512) ns = 512;
    for (int e = t; e < ns; e += 256) {
      unsigned ex = (p[2 * e] >> 7) & 0xFFu;
      if (ex < 64u) cnt++;
    }
  } else if (b == 8) {
    for (int e = t; e < 512; e += 256)
      if (spk_raw[2 * e + 1] != 0u) cnt++;
  } else {
    inbox[t] = 0;          // b == 9: zero the 256 per-tile inbox counters
    return;
  }
  part[t] = cnt;
  __syncthreads();
  #pragma unroll
  for (int o = 128; o > 0; o >>= 1) {
    if (t < o) part[t] += part[t + o];
    __syncthreads();
  }
  if (t == 0) {
    if (b < 8) flags[b] = (part[0] >= 2) ? 1 : 0;   // 1 = fp32
    else       flags[9] = (part[0] == 0) ? 1 : 0;   // 1 = int64 spk
  }
}

// ---------- adjacency from RAW inputs (identical values to canonical) ----------
__device__ __forceinline__ float adjr(int i, int j, int si, float m0, float m1, float m2,
                                      const void* __restrict__ spk,
                                      const void* __restrict__ mk, int fm, int fs) {
  if (i == j) return 1.0f;
  float t = expf(-0.1f * fabsf((float)(i - j)));
  if (ldspk(spk, j, fs) == si) return 0.8f * t;
  float ms = fabsf(m0 - ldx(mk, (long)j * 3, fm)) +
             fabsf(m1 - ldx(mk, (long)j * 3 + 1, fm)) +
             fabsf(m2 - ldx(mk, (long)j * 3 + 2, fm));
  return 0.5f * t * (1.0f - ms * (1.0f / 3.0f));
}

// ---------- canonicalize + prep2 + band rows (one full-occupancy kernel) ----------
#define FEATBLK 3712   // 4096*1856 / 8 / 256
#define NWBLK 1120     // (237568 + 32768 + 16384) / 256
__global__ __launch_bounds__(256) void prep(
    const void* feat, const void* Wp, const void* W1, const void* W2,
    const void* masks, const void* spk,
    const void* x0, const void* x1, const void* x2,
    const int* __restrict__ flags,
    u16* featc, u16* WpT, u16* W1T, u16* W2T,
    float* bp_c, float* b1c, float* b2c, u16* __restrict__ band) {
  __shared__ float part[256];
  __shared__ float invs;
  __shared__ float mxs[3][64];
  __shared__ int ord[3];
  const int blk = blockIdx.x, t = threadIdx.x;
  if (blk < FEATBLK) {
    if (!flags[0]) return;            // bf16 input: fused h0 reads feat directly
    long e = ((long)blk * 256 + t) * 8;
    const float* pf = (const float*)feat + e;
    u16 r[8];
    #pragma unroll
    for (int k = 0; k < 8; k++) r[k] = f2bf(pf[k]);
    *(bf16x8v*)(featc + e) = *(bf16x8v*)r;
    return;
  }
  if (blk < FEATBLK + NWBLK) {        // ---- weight transposes ----
    long e = (long)(blk - FEATBLK) * 256 + t;
    const int nWp = DIN * HN, nW1 = 2 * HN * HN;
    if (e < nWp) {  // e = input index k*HN+o; coalesced read, strided write
      int k = e >> 7, o = e & 127;
      WpT[(long)o * DIN + k] = f2bf(ldx(Wp, e, flags[2]));
      return;
    }
    e -= nWp;
    if (e < nW1) { int k = e >> 7, o = e & 127; W1T[(long)o * 256 + k] = f2bf(ldx(W1, e, flags[4])); return; }
    e -= nW1;
    { int k = e >> 7, o = e & 127; W2T[(long)o * 128 + k] = f2bf(ldx(W2, e, flags[6])); }
    return;
  }
  if (blk == FEATBLK + NWBLK) {       // ---- prep2 body ----
    const void* bs[3] = {x0, x1, x2};
    const int fl[3] = {flags[3], flags[5], flags[7]};
    if (t < 192) {
      int a = t / 64, e = t % 64;
      mxs[a][e] = fmaxf(fabsf(ldx(bs[a], e, fl[a])), fabsf(ldx(bs[a], e + 64, fl[a])));
    }
    __syncthreads();
    if (t == 0) {
      float mx[3];
      for (int a = 0; a < 3; a++) {
        float m = 0.f;
        for (int e = 0; e < 64; e++) m = fmaxf(m, mxs[a][e]);
        mx[a] = m;
      }
      int imin = 0, imax = 0;
      for (int k = 1; k < 3; k++) { if (mx[k] < mx[imin]) imin = k; if (mx[k] > mx[imax]) imax = k; }
      int imid = 3 - imin - imax;
      if (imin == imax) { imin = 0; imid = 1; imax = 2; }
      ord[0] = imin; ord[1] = imid; ord[2] = imax;
    }
    __syncthreads();
    if (t < HN) {
      bp_c[t] = ldx(bs[ord[0]], t, fl[ord[0]]);
      b1c[t]  = ldx(bs[ord[1]], t, fl[ord[1]]);
      b2c[t]  = ldx(bs[ord[2]], t, fl[ord[2]]);
    }
    return;
  }
  // ---- band row (bit-identical to build_band; raw-input reads) ----
  {
    const int i = blk - FEATBLK - NWBLK - 1;
    const int fm = flags[1], fs = flags[9];
    const int si = ldspk(spk, i, fs);
    const float m0 = ldx(masks, (long)i * 3, fm);
    const float m1 = ldx(masks, (long)i * 3 + 1, fm);
    const float m2 = ldx(masks, (long)i * 3 + 2, fm);
    float s = 0.f;
    for (int j = t; j < BN; j += 256) s += adjr(i, j, si, m0, m1, m2, spk, masks, fm, fs);
    part[t] = s;
    __syncthreads();
    if (t == 0) {
      float tot = 0.f;
      for (int k = 0; k < 256; k++) tot += part[k];   // serial: original order
      invs = 1.0f / (tot + 1e-8f);
    }
    __syncthreads();
    const float inv = invs;
    const int jbase = (i & ~15) - 128;
    for (int k = t; k < TILEW; k += 256) {
      int j = jbase + k;
      float v = 0.f;
      if (j >= 0 && j < BN) v = adjr(i, j, si, m0, m1, m2, spk, masks, fm, fs) * inv;
      band[(long)i * TILEW + k] = f2bf(v);
    }
  }
}

// snapshot buffer geometry (u16 units): [4096 guard][HN*BN data][4096 guard]
#define SNAP_ELEMS ((size_t)HN * BN + 8192)

// ---------- fused h0 + 16 RK4 stages (mailbox push-notification sync) ----------
// Snapshot k lives in its own single-write buffer: h0 -> snap 0; stage s
// output -> snap s+1. Stage s reads snap s from tiles tile-8..tile+11.
// Producer P pushes +1 to inboxes of consumers [P-11, P+8] after each publish.
// Consumer T proceeds when inbox[T] >= N_T*(s+1).
__global__ __launch_bounds__(512, 2) void fused_ode(
    const void* __restrict__ feat, const int* __restrict__ flags,
    const u16* __restrict__ featc, const u16* __restrict__ WpT,
    const float* __restrict__ bp_c, const u16* __restrict__ band,
    const u16* __restrict__ W1T, const u16* __restrict__ W2T,
    const float* __restrict__ b1c, const float* __restrict__ b2c,
    u16* __restrict__ hsb, float* __restrict__ outp,
    int* __restrict__ inbox) {
  __shared__ u16 hc[16][264];        // [hs(0:128) | agg(128:256)] i-major
  __shared__ u16 zt[16][136];        // tanh output i-major

  const int tid = threadIdx.x, w = tid >> 6, lane = tid & 63;
  const int m = lane & 15, q = lane >> 4;
  // XCD-aware tile swizzle (perf heuristic; correctness placement-independent)
  const int blk = blockIdx.x;
  const int tile = ((blk & 7) << 5) | (blk >> 3);
  const int r0 = tile * 16, jb = r0 - 128;
  const int n0 = w * 16 + m;
  const int i0 = r0 + q * 4;
  const long base = (long)n0 * BN + i0;

  // exact in-range producer count for this tile's window [tile-8, tile+11]
  const int plo = (tile - 8 < 0) ? 0 : tile - 8;
  const int phi = (tile + 11 > 255) ? 255 : tile + 11;
  const int nprod = phi - plo + 1;
  // this thread's consumer push target (lanes/tids 0..19): [tile-11, tile+8]
  const int cons = tile - 11 + tid;
  const int cvalid = (tid < 20) && (cons >= 0) && (cons < 256);

  // persistent operand registers (loaded once, reused all 16 stages)
  bf16x8v w1r[8], w2r[4], bnd[10];
  {
    const u16* w1row = W1T + (long)n0 * 256;
    #pragma unroll
    for (int kf = 0; kf < 8; kf++) {
      int k = (kf >> 1) * 64 + (kf & 1) * 32 + q * 8;
      w1r[kf] = *(const bf16x8v*)(w1row + k);
    }
    const u16* w2row = W2T + (long)n0 * 128;
    #pragma unroll
    for (int kf = 0; kf < 4; kf++) {
      int k = (kf >> 1) * 64 + (kf & 1) * 32 + q * 8;
      w2r[kf] = *(const bf16x8v*)(w2row + k);
    }
    const u16* bandrow = band + (long)tile * 5120 + m * TILEW;
    #pragma unroll
    for (int kf = 0; kf < 10; kf++) {
      int k = (kf >> 1) * 64 + (kf & 1) * 32 + q * 8;
      bnd[kf] = *(const bf16x8v*)(bandrow + k);
    }
  }
  const float b1v = b1c[n0], b2v = b2c[n0];

  // ---- h0 = feat @ Wp + bp (identical bits: featc when fp32, raw when bf16) ----
  f32x4 hb;
  {
    const u16* fbase = flags[0] ? featc : (const u16*)feat;
    f32x4 a0 = {0, 0, 0, 0};
    const u16* arow = fbase + (long)(r0 + m) * DIN;
    const u16* brow = WpT + (long)n0 * DIN;
    #pragma unroll 4
    for (int kf = 0; kf < 58; kf++) {   // 58 * 32 = 1856
      int k = (kf >> 1) * 64 + (kf & 1) * 32 + q * 8;
      bf16x8v a = *(const bf16x8v*)(arow + k);
      bf16x8v b = *(const bf16x8v*)(brow + k);
      a0 = MFMA16(a, b, a0);
    }
    a0 += bp_c[n0];
    hb = a0;
  }
  f32x4 acc = {0, 0, 0, 0};
  {
    u16* snap0 = hsb + 4096;                           // snapshot 0 data
    ushort4 hsv;
    hsv.x = f2bf(hb[0]); hsv.y = f2bf(hb[1]); hsv.z = f2bf(hb[2]); hsv.w = f2bf(hb[3]);
    union { ushort4 s; u64 q8; } pu; pu.s = hsv;
    cstore8(&snap0[base], pu.q8);                      // cross-block snapshot 0
    hc[q * 4 + 0][n0] = hsv.x; hc[q * 4 + 1][n0] = hsv.y;  // own-block, direct
    hc[q * 4 + 2][n0] = hsv.z; hc[q * 4 + 3][n0] = hsv.w;
  }
  asm volatile("s_waitcnt vmcnt(0)" ::: "memory");     // hs stores at LLC
  __syncthreads();
  if (cvalid)
    __hip_atomic_fetch_add(&inbox[cons], 1, __ATOMIC_RELAXED, __HIP_MEMORY_SCOPE_AGENT);

  const float dt6 = 0.25f / 6.0f;

  #pragma unroll 1
  for (int s = 0; s < 16; s++) {
    const int sub = s & 3;

    // GEMM1 own-hs half (kf 0..3) — no neighbor dependency; overlaps handoff
    f32x4 z0 = {0, 0, 0, 0};
    #pragma unroll
    for (int kf = 0; kf < 4; kf++) {
      int k = (kf >> 1) * 64 + (kf & 1) * 32 + q * 8;
      bf16x8v a = *(const bf16x8v*)&hc[m][k];
      z0 = MFMA16(a, w1r[kf], z0);
    }

    // ---- single-poller wait: inbox reaches nprod*(s+1) ----
    if (tid == 0) {
      const int tgt = nprod * (s + 1);
      while (__hip_atomic_load(&inbox[tile], __ATOMIC_RELAXED,
                               __HIP_MEMORY_SCOPE_AGENT) < tgt)
        __builtin_amdgcn_s_sleep(1);
    }
    __syncthreads();

    // phase 1: banded agg — A from band regs, B via plain cached loads
    // (snapshot buffer is single-write: no stale copy can exist).
    f32x4 g0 = {0, 0, 0, 0};
    const u16* hrow = hsb + (size_t)s * SNAP_ELEMS + 4096 + (long)n0 * BN + jb;
    #pragma unroll
    for (int kf = 0; kf < 10; kf++) {
      int k = (kf >> 1) * 64 + (kf & 1) * 32 + q * 8;
      bf16x8v b = *(const bf16x8v*)(hrow + k);
      g0 = MFMA16(bnd[kf], b, g0);
    }
    #pragma unroll
    for (int r = 0; r < 4; r++) hc[q * 4 + r][128 + n0] = f2bf(g0[r]);
    __syncthreads();

    // GEMM1 agg half (kf 4..7) — completes z0 in original accumulation order
    #pragma unroll
    for (int kf = 4; kf < 8; kf++) {
      int k = (kf >> 1) * 64 + (kf & 1) * 32 + q * 8;
      bf16x8v a = *(const bf16x8v*)&hc[m][k];
      z0 = MFMA16(a, w1r[kf], z0);
    }
    #pragma unroll
    for (int r = 0; r < 4; r++) zt[q * 4 + r][n0] = f2bf(tanhf(z0[r] + b1v));
    __syncthreads();

    // GEMM2: k = z @ W2 — A from LDS, B from persistent regs
    f32x4 k0 = {0, 0, 0, 0};
    #pragma unroll
    for (int kf = 0; kf < 4; kf++) {
      int k = (kf >> 1) * 64 + (kf & 1) * 32 + q * 8;
      bf16x8v a = *(const bf16x8v*)&zt[m][k];
      k0 = MFMA16(a, w2r[kf], k0);
    }
    f32x4 kv = k0;
    kv += b2v;

    // RK4 update — identical fp32 expression order to round 9
    f32x4 hn;
    if (sub == 0)      { acc = 1.f * kv;  hn = hb + 0.125f * kv; }
    else if (sub == 1) { acc += 2.f * kv; hn = hb + 0.125f * kv; }
    else if (sub == 2) { acc += 2.f * kv; hn = hb + 0.25f  * kv; }
    else {
      hn = hb + dt6 * (acc + kv);
      hb = hn;
      if (s == 15) {
        #pragma unroll
        for (int r = 0; r < 4; r++) outp[(long)(i0 + r) * HN + n0] = hn[r];  // fp32
      }
    }

    if (s < 15) {
      // publish snapshot s+1: LLC store (neighbors) + LDS left half (own)
      u16* snapw = hsb + (size_t)(s + 1) * SNAP_ELEMS + 4096;
      ushort4 hsv;
      hsv.x = f2bf(hn[0]); hsv.y = f2bf(hn[1]); hsv.z = f2bf(hn[2]); hsv.w = f2bf(hn[3]);
      union { ushort4 s4; u64 q8; } pu; pu.s4 = hsv;
      cstore8(&snapw[base], pu.q8);
      hc[q * 4 + 0][n0] = hsv.x; hc[q * 4 + 1][n0] = hsv.y;
      hc[q * 4 + 2][n0] = hsv.z; hc[q * 4 + 3][n0] = hsv.w;
      asm volatile("s_waitcnt vmcnt(0)" ::: "memory");   // hs stores at LLC
      __syncthreads();
      if (cvalid)
        __hip_atomic_fetch_add(&inbox[cons], 1, __ATOMIC_RELAXED, __HIP_MEMORY_SCOPE_AGENT);
    }
  }
}

// ---------- launch ----------
extern "C" void kernel_launch(void* const* d_in, const int* in_sizes, int n_in,
                              void* d_out, int out_size, void* d_ws, size_t ws_size,
                              hipStream_t stream) {
  const void* feat = nullptr; const void* spk = nullptr; const void* masks = nullptr;
  const void* Wp = nullptr; const void* W1 = nullptr; const void* W2 = nullptr;
  const void* bias[3] = {nullptr, nullptr, nullptr};
  int nb = 0;
  for (int k = 0; k < n_in; k++) {
    switch (in_sizes[k]) {
      case BN * DIN:    feat = d_in[k]; break;
      case BN:          spk = d_in[k]; break;
      case BN * 3:      masks = d_in[k]; break;
      case DIN * HN:    Wp = d_in[k]; break;
      case 2 * HN * HN: W1 = d_in[k]; break;
      case HN * HN:     W2 = d_in[k]; break;
      default:          if (in_sizes[k] == HN && nb < 3) bias[nb++] = d_in[k]; break;
    }
  }
  float* out = (float*)d_out;

  char* p = (char*)d_ws;
  int*   flags   = (int*)p;   p += 64;
  float* bp_c    = (float*)p; p += 512;
  float* b1c     = (float*)p; p += 512;
  float* b2c     = (float*)p; p += 512;
  int*   inbox   = (int*)p;   p += 1024;                    // 256 inbox counters
  u16*   featc   = (u16*)p;   p += (size_t)BN * DIN * 2;    // 15,204,352
  u16*   WpT     = (u16*)p;   p += (size_t)HN * DIN * 2;
  u16*   W1T     = (u16*)p;   p += (size_t)HN * 256 * 2;
  u16*   W2T     = (u16*)p;   p += (size_t)HN * HN * 2;
  u16*   band    = (u16*)p;   p += (size_t)BN * TILEW * 2;
  u16*   hsb     = (u16*)p;   p += 16 * SNAP_ELEMS * 2;     // 16 snapshots ~17 MB
  (void)ws_size; (void)out_size;                            // total ~36 MB

  detect<<<10, 256, 0, stream>>>(feat, masks, Wp, bias[0], W1, bias[1], W2, bias[2],
                                 (const unsigned*)spk, flags, inbox);
  prep<<<FEATBLK + NWBLK + 1 + BN, 256, 0, stream>>>(
      feat, Wp, W1, W2, masks, spk, bias[0], bias[1], bias[2], flags,
      featc, WpT, W1T, W2T, bp_c, b1c, b2c, band);

  // Regular launch: 256 blocks on 256 CUs (1 block/CU by resource fit) —
  // co-residency without the cooperative-launch overhead.
  fused_ode<<<dim3(BN / 16), dim3(512), 0, stream>>>(
      feat, flags, featc, WpT, bp_c, band, W1T, W2T, b1c, b2c,
      hsb, out, inbox);
}

// Round 17
// 225.203 us; speedup vs baseline: 1.3145x; 1.1046x over previous
//
#include <hip/hip_runtime.h>

// DGODE — round 19 (4th submit; rounds 14-16 failed on infra, never measured).
//   Pad inbox counters to 128B (kill LLC line contention).
//   r18 measured: fused_ode 133.5us (~7.8us/stage vs ~3us latency model).
//   Revised theory: inbox[256] packs 16 counters/64B line -> 5120 fetch_adds
//   per stage serialize ~320-deep on each of 16 lines at the LLC bank, and
//   256 pollers contend on the same lines. Fix: stride counters by 128B —
//   ~20 adds/line/stage, producer's 20 adds hit 20 different lines (parallel
//   banks), each poller owns a private line. Protocol/visibility unchanged
//   from r18 (drain->barrier->fetch_add; single poller; single-write
//   snapshots -> plain cached window loads).
// Same MFMA sequence per (m,n,k), same fp32 expression order => bit-identical
// output (absmax 0.015625).

typedef unsigned short u16;
typedef unsigned long long u64;
typedef __attribute__((ext_vector_type(8))) short bf16x8v;
typedef __attribute__((ext_vector_type(4))) float f32x4;

#define MFMA16(a, b, c) __builtin_amdgcn_mfma_f32_16x16x32_bf16(a, b, c, 0, 0, 0)

#define BN 4096
#define HN 128
#define DIN 1856
#define TILEW 320
#define IBSTRIDE 32   // inbox counter stride in ints (128B) — one LLC line each

__device__ __forceinline__ float bf2f(u16 u) {
  union { unsigned u; float f; } v; v.u = ((unsigned)u) << 16; return v.f;
}
__device__ __forceinline__ u16 f2bf(float f) {
  union { float f; unsigned u; } v; v.f = f;
  unsigned u = v.u;
  return (u16)((u + 0x7fffu + ((u >> 16) & 1u)) >> 16);  // RNE
}
__device__ __forceinline__ float ldx(const void* p, long idx, int isf) {
  return isf ? ((const float*)p)[idx] : bf2f(((const u16*)p)[idx]);
}
__device__ __forceinline__ int ldspk(const void* spk, int j, int i64) {
  return i64 ? ((const int*)spk)[2 * j] : ((const int*)spk)[j];
}

// coherent (LLC-point) 8B store, no cache maintenance (producer publish path)
__device__ __forceinline__ void cstore8(u16* p, u64 v) {
  __hip_atomic_store((u64*)p, v, __ATOMIC_RELAXED, __HIP_MEMORY_SCOPE_AGENT);
}

// ---------- per-array dtype detection (parallel) + inbox zeroing ----------
__global__ __launch_bounds__(256) void detect(
    const void* a0, const void* a1, const void* a2, const void* a3,
    const void* a4, const void* a5, const void* a6, const void* a7,
    const unsigned* spk_raw, int* flags, int* inbox) {
  __shared__ int part[256];
  const int b = blockIdx.x, t = threadIdx.x;
  int cnt = 0;
  if (b < 8) {
    const void* arr[8] = {a0, a1, a2, a3, a4, a5, a6, a7};
    const int nel[8] = {BN * DIN, BN * 3, DIN * HN, HN, 2 * HN * HN, HN, HN * HN, HN};
    const u16* p = (const u16*)arr[b];
    int ns = nel[b] / 2; if (ns > 512) ns = 512;
    for (int e = t; e < ns; e += 256) {
      unsigned ex = (p[2 * e] >> 7) & 0xFFu;
      if (ex < 64u) cnt++;
    }
  } else if (b == 8) {
    for (int e = t; e < 512; e += 256)
      if (spk_raw[2 * e + 1] != 0u) cnt++;
  } else {
    inbox[t * IBSTRIDE] = 0;   // b == 9: zero 256 padded inbox counters
    return;
  }
  part[t] = cnt;
  __syncthreads();
  #pragma unroll
  for (int o = 128; o > 0; o >>= 1) {
    if (t < o) part[t] += part[t + o];
    __syncthreads();
  }
  if (t == 0) {
    if (b < 8) flags[b] = (part[0] >= 2) ? 1 : 0;   // 1 = fp32
    else       flags[9] = (part[0] == 0) ? 1 : 0;   // 1 = int64 spk
  }
}

// ---------- adjacency from RAW inputs (identical values to canonical) ----------
__device__ __forceinline__ float adjr(int i, int j, int si, float m0, float m1, float m2,
                                      const void* __restrict__ spk,
                                      const void* __restrict__ mk, int fm, int fs) {
  if (i == j) return 1.0f;
  float t = expf(-0.1f * fabsf((float)(i - j)));
  if (ldspk(spk, j, fs) == si) return 0.8f * t;
  float ms = fabsf(m0 - ldx(mk, (long)j * 3, fm)) +
             fabsf(m1 - ldx(mk, (long)j * 3 + 1, fm)) +
             fabsf(m2 - ldx(mk, (long)j * 3 + 2, fm));
  return 0.5f * t * (1.0f - ms * (1.0f / 3.0f));
}

// ---------- canonicalize + prep2 + band rows (one full-occupancy kernel) ----------
#define FEATBLK 3712   // 4096*1856 / 8 / 256
#define NWBLK 1120     // (237568 + 32768 + 16384) / 256
__global__ __launch_bounds__(256) void prep(
    const void* feat, const void* Wp, const void* W1, const void* W2,
    const void* masks, const void* spk,
    const void* x0, const void* x1, const void* x2,
    const int* __restrict__ flags,
    u16* featc, u16* WpT, u16* W1T, u16* W2T,
    float* bp_c, float* b1c, float* b2c, u16* __restrict__ band) {
  __shared__ float part[256];
  __shared__ float invs;
  __shared__ float mxs[3][64];
  __shared__ int ord[3];
  const int blk = blockIdx.x, t = threadIdx.x;
  if (blk < FEATBLK) {
    if (!flags[0]) return;            // bf16 input: fused h0 reads feat directly
    long e = ((long)blk * 256 + t) * 8;
    const float* pf = (const float*)feat + e;
    u16 r[8];
    #pragma unroll
    for (int k = 0; k < 8; k++) r[k] = f2bf(pf[k]);
    *(bf16x8v*)(featc + e) = *(bf16x8v*)r;
    return;
  }
  if (blk < FEATBLK + NWBLK) {        // ---- weight transposes ----
    long e = (long)(blk - FEATBLK) * 256 + t;
    const int nWp = DIN * HN, nW1 = 2 * HN * HN;
    if (e < nWp) {  // e = input index k*HN+o; coalesced read, strided write
      int k = e >> 7, o = e & 127;
      WpT[(long)o * DIN + k] = f2bf(ldx(Wp, e, flags[2]));
      return;
    }
    e -= nWp;
    if (e < nW1) { int k = e >> 7, o = e & 127; W1T[(long)o * 256 + k] = f2bf(ldx(W1, e, flags[4])); return; }
    e -= nW1;
    { int k = e >> 7, o = e & 127; W2T[(long)o * 128 + k] = f2bf(ldx(W2, e, flags[6])); }
    return;
  }
  if (blk == FEATBLK + NWBLK) {       // ---- prep2 body ----
    const void* bs[3] = {x0, x1, x2};
    const int fl[3] = {flags[3], flags[5], flags[7]};
    if (t < 192) {
      int a = t / 64, e = t % 64;
      mxs[a][e] = fmaxf(fabsf(ldx(bs[a], e, fl[a])), fabsf(ldx(bs[a], e + 64, fl[a])));
    }
    __syncthreads();
    if (t == 0) {
      float mx[3];
      for (int a = 0; a < 3; a++) {
        float m = 0.f;
        for (int e = 0; e < 64; e++) m = fmaxf(m, mxs[a][e]);
        mx[a] = m;
      }
      int imin = 0, imax = 0;
      for (int k = 1; k < 3; k++) { if (mx[k] < mx[imin]) imin = k; if (mx[k] > mx[imax]) imax = k; }
      int imid = 3 - imin - imax;
      if (imin == imax) { imin = 0; imid = 1; imax = 2; }
      ord[0] = imin; ord[1] = imid; ord[2] = imax;
    }
    __syncthreads();
    if (t < HN) {
      bp_c[t] = ldx(bs[ord[0]], t, fl[ord[0]]);
      b1c[t]  = ldx(bs[ord[1]], t, fl[ord[1]]);
      b2c[t]  = ldx(bs[ord[2]], t, fl[ord[2]]);
    }
    return;
  }
  // ---- band row (bit-identical to build_band; raw-input reads) ----
  {
    const int i = blk - FEATBLK - NWBLK - 1;
    const int fm = flags[1], fs = flags[9];
    const int si = ldspk(spk, i, fs);
    const float m0 = ldx(masks, (long)i * 3, fm);
    const float m1 = ldx(masks, (long)i * 3 + 1, fm);
    const float m2 = ldx(masks, (long)i * 3 + 2, fm);
    float s = 0.f;
    for (int j = t; j < BN; j += 256) s += adjr(i, j, si, m0, m1, m2, spk, masks, fm, fs);
    part[t] = s;
    __syncthreads();
    if (t == 0) {
      float tot = 0.f;
      for (int k = 0; k < 256; k++) tot += part[k];   // serial: original order
      invs = 1.0f / (tot + 1e-8f);
    }
    __syncthreads();
    const float inv = invs;
    const int jbase = (i & ~15) - 128;
    for (int k = t; k < TILEW; k += 256) {
      int j = jbase + k;
      float v = 0.f;
      if (j >= 0 && j < BN) v = adjr(i, j, si, m0, m1, m2, spk, masks, fm, fs) * inv;
      band[(long)i * TILEW + k] = f2bf(v);
    }
  }
}

// snapshot buffer geometry (u16 units): [4096 guard][HN*BN data][4096 guard]
#define SNAP_ELEMS ((size_t)HN * BN + 8192)

// ---------- fused h0 + 16 RK4 stages (padded-mailbox push sync) ----------
// Snapshot k lives in its own single-write buffer: h0 -> snap 0; stage s
// output -> snap s+1. Stage s reads snap s from tiles tile-8..tile+11.
// Producer P pushes +1 to padded inboxes of consumers [P-11, P+8] per publish.
// Consumer T proceeds when inbox[T*IBSTRIDE] >= N_T*(s+1).
__global__ __launch_bounds__(512, 2) void fused_ode(
    const void* __restrict__ feat, const int* __restrict__ flags,
    const u16* __restrict__ featc, const u16* __restrict__ WpT,
    const float* __restrict__ bp_c, const u16* __restrict__ band,
    const u16* __restrict__ W1T, const u16* __restrict__ W2T,
    const float* __restrict__ b1c, const float* __restrict__ b2c,
    u16* __restrict__ hsb, float* __restrict__ outp,
    int* __restrict__ inbox) {
  __shared__ u16 hc[16][264];        // [hs(0:128) | agg(128:256)] i-major
  __shared__ u16 zt[16][136];        // tanh output i-major

  const int tid = threadIdx.x, w = tid >> 6, lane = tid & 63;
  const int m = lane & 15, q = lane >> 4;
  // XCD-aware tile swizzle (perf heuristic; correctness placement-independent)
  const int blk = blockIdx.x;
  const int tile = ((blk & 7) << 5) | (blk >> 3);
  const int r0 = tile * 16, jb = r0 - 128;
  const int n0 = w * 16 + m;
  const int i0 = r0 + q * 4;
  const long base = (long)n0 * BN + i0;

  // exact in-range producer count for this tile's window [tile-8, tile+11]
  const int plo = (tile - 8 < 0) ? 0 : tile - 8;
  const int phi = (tile + 11 > 255) ? 255 : tile + 11;
  const int nprod = phi - plo + 1;
  // this thread's consumer push target (tids 0..19): [tile-11, tile+8]
  const int cons = tile - 11 + tid;
  const int cvalid = (tid < 20) && (cons >= 0) && (cons < 256);

  // persistent operand registers (loaded once, reused all 16 stages)
  bf16x8v w1r[8], w2r[4], bnd[10];
  {
    const u16* w1row = W1T + (long)n0 * 256;
    #pragma unroll
    for (int kf = 0; kf < 8; kf++) {
      int k = (kf >> 1) * 64 + (kf & 1) * 32 + q * 8;
      w1r[kf] = *(const bf16x8v*)(w1row + k);
    }
    const u16* w2row = W2T + (long)n0 * 128;
    #pragma unroll
    for (int kf = 0; kf < 4; kf++) {
      int k = (kf >> 1) * 64 + (kf & 1) * 32 + q * 8;
      w2r[kf] = *(const bf16x8v*)(w2row + k);
    }
    const u16* bandrow = band + (long)tile * 5120 + m * TILEW;
    #pragma unroll
    for (int kf = 0; kf < 10; kf++) {
      int k = (kf >> 1) * 64 + (kf & 1) * 32 + q * 8;
      bnd[kf] = *(const bf16x8v*)(bandrow + k);
    }
  }
  const float b1v = b1c[n0], b2v = b2c[n0];

  // ---- h0 = feat @ Wp + bp (identical bits: featc when fp32, raw when bf16) ----
  f32x4 hb;
  {
    const u16* fbase = flags[0] ? featc : (const u16*)feat;
    f32x4 a0 = {0, 0, 0, 0};
    const u16* arow = fbase + (long)(r0 + m) * DIN;
    const u16* brow = WpT + (long)n0 * DIN;
    #pragma unroll 4
    for (int kf = 0; kf < 58; kf++) {   // 58 * 32 = 1856
      int k = (kf >> 1) * 64 + (kf & 1) * 32 + q * 8;
      bf16x8v a = *(const bf16x8v*)(arow + k);
      bf16x8v b = *(const bf16x8v*)(brow + k);
      a0 = MFMA16(a, b, a0);
    }
    a0 += bp_c[n0];
    hb = a0;
  }
  f32x4 acc = {0, 0, 0, 0};
  {
    u16* snap0 = hsb + 4096;                           // snapshot 0 data
    ushort4 hsv;
    hsv.x = f2bf(hb[0]); hsv.y = f2bf(hb[1]); hsv.z = f2bf(hb[2]); hsv.w = f2bf(hb[3]);
    union { ushort4 s; u64 q8; } pu; pu.s = hsv;
    cstore8(&snap0[base], pu.q8);                      // cross-block snapshot 0
    hc[q * 4 + 0][n0] = hsv.x; hc[q * 4 + 1][n0] = hsv.y;  // own-block, direct
    hc[q * 4 + 2][n0] = hsv.z; hc[q * 4 + 3][n0] = hsv.w;
  }
  asm volatile("s_waitcnt vmcnt(0)" ::: "memory");     // hs stores at LLC
  __syncthreads();
  if (cvalid)
    __hip_atomic_fetch_add(&inbox[cons * IBSTRIDE], 1, __ATOMIC_RELAXED,
                           __HIP_MEMORY_SCOPE_AGENT);

  const float dt6 = 0.25f / 6.0f;

  #pragma unroll 1
  for (int s = 0; s < 16; s++) {
    const int sub = s & 3;

    // GEMM1 own-hs half (kf 0..3) — no neighbor dependency; overlaps handoff
    f32x4 z0 = {0, 0, 0, 0};
    #pragma unroll
    for (int kf = 0; kf < 4; kf++) {
      int k = (kf >> 1) * 64 + (kf & 1) * 32 + q * 8;
      bf16x8v a = *(const bf16x8v*)&hc[m][k];
      z0 = MFMA16(a, w1r[kf], z0);
    }

    // ---- single-poller wait on private padded line ----
    if (tid == 0) {
      const int tgt = nprod * (s + 1);
      while (__hip_atomic_load(&inbox[tile * IBSTRIDE], __ATOMIC_RELAXED,
                               __HIP_MEMORY_SCOPE_AGENT) < tgt)
        __builtin_amdgcn_s_sleep(1);
    }
    __syncthreads();

    // phase 1: banded agg — A from band regs, B via plain cached loads
    // (snapshot buffer is single-write: no stale copy can exist).
    f32x4 g0 = {0, 0, 0, 0};
    const u16* hrow = hsb + (size_t)s * SNAP_ELEMS + 4096 + (long)n0 * BN + jb;
    #pragma unroll
    for (int kf = 0; kf < 10; kf++) {
      int k = (kf >> 1) * 64 + (kf & 1) * 32 + q * 8;
      bf16x8v b = *(const bf16x8v*)(hrow + k);
      g0 = MFMA16(bnd[kf], b, g0);
    }
    #pragma unroll
    for (int r = 0; r < 4; r++) hc[q * 4 + r][128 + n0] = f2bf(g0[r]);
    __syncthreads();

    // GEMM1 agg half (kf 4..7) — completes z0 in original accumulation order
    #pragma unroll
    for (int kf = 4; kf < 8; kf++) {
      int k = (kf >> 1) * 64 + (kf & 1) * 32 + q * 8;
      bf16x8v a = *(const bf16x8v*)&hc[m][k];
      z0 = MFMA16(a, w1r[kf], z0);
    }
    #pragma unroll
    for (int r = 0; r < 4; r++) zt[q * 4 + r][n0] = f2bf(tanhf(z0[r] + b1v));
    __syncthreads();

    // GEMM2: k = z @ W2 — A from LDS, B from persistent regs
    f32x4 k0 = {0, 0, 0, 0};
    #pragma unroll
    for (int kf = 0; kf < 4; kf++) {
      int k = (kf >> 1) * 64 + (kf & 1) * 32 + q * 8;
      bf16x8v a = *(const bf16x8v*)&zt[m][k];
      k0 = MFMA16(a, w2r[kf], k0);
    }
    f32x4 kv = k0;
    kv += b2v;

    // RK4 update — identical fp32 expression order to round 9
    f32x4 hn;
    if (sub == 0)      { acc = 1.f * kv;  hn = hb + 0.125f * kv; }
    else if (sub == 1) { acc += 2.f * kv; hn = hb + 0.125f * kv; }
    else if (sub == 2) { acc += 2.f * kv; hn = hb + 0.25f  * kv; }
    else {
      hn = hb + dt6 * (acc + kv);
      hb = hn;
      if (s == 15) {
        #pragma unroll
        for (int r = 0; r < 4; r++) outp[(long)(i0 + r) * HN + n0] = hn[r];  // fp32
      }
    }

    if (s < 15) {
      // publish snapshot s+1: LLC store (neighbors) + LDS left half (own)
      u16* snapw = hsb + (size_t)(s + 1) * SNAP_ELEMS + 4096;
      ushort4 hsv;
      hsv.x = f2bf(hn[0]); hsv.y = f2bf(hn[1]); hsv.z = f2bf(hn[2]); hsv.w = f2bf(hn[3]);
      union { ushort4 s4; u64 q8; } pu; pu.s4 = hsv;
      cstore8(&snapw[base], pu.q8);
      hc[q * 4 + 0][n0] = hsv.x; hc[q * 4 + 1][n0] = hsv.y;
      hc[q * 4 + 2][n0] = hsv.z; hc[q * 4 + 3][n0] = hsv.w;
      asm volatile("s_waitcnt vmcnt(0)" ::: "memory");   // hs stores at LLC
      __syncthreads();
      if (cvalid)
        __hip_atomic_fetch_add(&inbox[cons * IBSTRIDE], 1, __ATOMIC_RELAXED,
                               __HIP_MEMORY_SCOPE_AGENT);
    }
  }
}

// ---------- launch ----------
extern "C" void kernel_launch(void* const* d_in, const int* in_sizes, int n_in,
                              void* d_out, int out_size, void* d_ws, size_t ws_size,
                              hipStream_t stream) {
  const void* feat = nullptr; const void* spk = nullptr; const void* masks = nullptr;
  const void* Wp = nullptr; const void* W1 = nullptr; const void* W2 = nullptr;
  const void* bias[3] = {nullptr, nullptr, nullptr};
  int nb = 0;
  for (int k = 0; k < n_in; k++) {
    switch (in_sizes[k]) {
      case BN * DIN:    feat = d_in[k]; break;
      case BN:          spk = d_in[k]; break;
      case BN * 3:      masks = d_in[k]; break;
      case DIN * HN:    Wp = d_in[k]; break;
      case 2 * HN * HN: W1 = d_in[k]; break;
      case HN * HN:     W2 = d_in[k]; break;
      default:          if (in_sizes[k] == HN && nb < 3) bias[nb++] = d_in[k]; break;
    }
  }
  float* out = (float*)d_out;

  char* p = (char*)d_ws;
  int*   flags   = (int*)p;   p += 64;
  float* bp_c    = (float*)p; p += 512;
  float* b1c     = (float*)p; p += 512;
  float* b2c     = (float*)p; p += 512;
  int*   inbox   = (int*)p;   p += 256 * IBSTRIDE * 4;      // 256 padded counters (32KB)
  u16*   featc   = (u16*)p;   p += (size_t)BN * DIN * 2;    // 15,204,352
  u16*   WpT     = (u16*)p;   p += (size_t)HN * DIN * 2;
  u16*   W1T     = (u16*)p;   p += (size_t)HN * 256 * 2;
  u16*   W2T     = (u16*)p;   p += (size_t)HN * HN * 2;
  u16*   band    = (u16*)p;   p += (size_t)BN * TILEW * 2;
  u16*   hsb     = (u16*)p;   p += 16 * SNAP_ELEMS * 2;     // 16 snapshots ~17 MB
  (void)ws_size; (void)out_size;                            // total ~36 MB

  detect<<<10, 256, 0, stream>>>(feat, masks, Wp, bias[0], W1, bias[1], W2, bias[2],
                                 (const unsigned*)spk, flags, inbox);
  prep<<<FEATBLK + NWBLK + 1 + BN, 256, 0, stream>>>(
      feat, Wp, W1, W2, masks, spk, bias[0], bias[1], bias[2], flags,
      featc, WpT, W1T, W2T, bp_c, b1c, b2c, band);

  // Regular launch: 256 blocks on 256 CUs (1 block/CU by resource fit) —
  // co-residency without the cooperative-launch overhead.
  fused_ode<<<dim3(BN / 16), dim3(512), 0, stream>>>(
      feat, flags, featc, WpT, bp_c, band, W1T, W2T, b1c, b2c,
      hsb, out, inbox);
}